// Round 9
// baseline (343.880 us; speedup 1.0000x reference)
//
#include <hip/hip_runtime.h>
#include <hip/hip_bf16.h>

// Problem constants: B=2048, S=32, H=256, NSEG=65536, NNBR=524288
#define BB    2048
#define SS    32
#define HH    256
#define NSEGC 65536
#define NNBRC 524288
#define NXCD  8
#define SPW   4          // segments per wave (consecutive -> contiguous idx range)

using f32x4 = __attribute__((ext_vector_type(4))) float;

// ---------------------------------------------------------------------------
// Kernel 1: per-segment lower_bound over sorted segment_ids -> start[NSEG+1]
//           + folded-in float4 copy of s_hist_dt into the output tail.
// ---------------------------------------------------------------------------
__global__ __launch_bounds__(256) void seg_bounds_dt_kernel(
    const int*   __restrict__ segment_ids,
    int*         __restrict__ start,
    const float* __restrict__ dt,
    float*       __restrict__ out_tail)
{
    const int i = blockIdx.x * blockDim.x + threadIdx.x;

    if (i < NSEGC / 4) {
        const f32x4 v = reinterpret_cast<const f32x4*>(dt)[i];
        __builtin_nontemporal_store(v, reinterpret_cast<f32x4*>(out_tail) + i);
    }

    if (i > NSEGC) return;
    int lo = 0, hi = NNBRC;
    while (lo < hi) {
        const int mid = (lo + hi) >> 1;
        if (segment_ids[mid] < i) lo = mid + 1;
        else hi = mid;
    }
    start[i] = lo;
}

// ---------------------------------------------------------------------------
// Kernel 2 (WRITE-streaming, runs FIRST): replicate ent/rel rows across time.
// One block per batch b; NT stores so the 134 MB stream doesn't (ideally)
// allocate, and anything it does allocate is evicted before the mean phase.
// ---------------------------------------------------------------------------
__global__ __launch_bounds__(256) void broadcast_kernel(
    const int*   __restrict__ s_tem,
    const int*   __restrict__ r_tem,
    const float* __restrict__ ent,
    const float* __restrict__ rel,
    float*       __restrict__ out)
{
    const int b    = blockIdx.x;           // 0..2047
    const int wid  = threadIdx.x >> 6;     // 0..3
    const int lane = threadIdx.x & 63;

    const int e = s_tem[b];
    const int r = r_tem[b];
    const f32x4 ev = *reinterpret_cast<const f32x4*>(ent + (size_t)e * HH + lane * 4);
    const f32x4 rv = *reinterpret_cast<const f32x4*>(rel + (size_t)r * HH + lane * 4);

    float* ob = out + (size_t)b * SS * (3 * HH);
    #pragma unroll
    for (int s = wid; s < SS; s += 4) {
        float* os = ob + (size_t)s * (3 * HH);
        __builtin_nontemporal_store(ev, reinterpret_cast<f32x4*>(os + HH) + lane);
        __builtin_nontemporal_store(rv, reinterpret_cast<f32x4*>(os + 2 * HH) + lane);
    }
}

// ---------------------------------------------------------------------------
// Kernel 3 (gather phase, runs LAST): one wave = 4 consecutive segments.
// During this phase the live working set is table (102 MB) + mean writes
// (67 MB NT) = 169 MB < 256 MB L3, so gather re-references should be
// L3-resident. 8 independent 1KB row-gathers in flight; bucket-select
// accumulation via scalar (readfirstlane) boundaries.
// ---------------------------------------------------------------------------
__global__ __launch_bounds__(256) void mean_kernel(
    const int*   __restrict__ neighbor_idx,
    const float* __restrict__ ent,
    const int*   __restrict__ start,
    float*       __restrict__ out)
{
    // chunked XCD swizzle
    const int chunkw = gridDim.x / NXCD;
    const int wg   = (blockIdx.x % NXCD) * chunkw + blockIdx.x / NXCD;
    const int wave = wg * 4 + (threadIdx.x >> 6);      // 0..16383
    const int lane = threadIdx.x & 63;
    const int seg0 = wave * SPW;

    // 5 boundaries start[seg0..seg0+4] via one lane-load, hoisted to SGPRs
    const int sv = start[seg0 + min(lane, SPW)];
    const int p0 = __builtin_amdgcn_readfirstlane(__shfl(sv, 0));
    const int p1 = __builtin_amdgcn_readfirstlane(__shfl(sv, 1));
    const int p2 = __builtin_amdgcn_readfirstlane(__shfl(sv, 2));
    const int p3 = __builtin_amdgcn_readfirstlane(__shfl(sv, 3));
    const int p4 = __builtin_amdgcn_readfirstlane(__shfl(sv, 4));
    const int total = p4 - p0;
    const int r1 = p1 - p0, r2 = p2 - p0, r3 = p3 - p0;

    f32x4 a0 = {0.f,0.f,0.f,0.f}, a1 = a0, a2 = a0, a3 = a0;

    for (int base = 0; base < total; base += 64) {
        const int cnt = min(64, total - base);
        int myidx = 0;
        if (lane < cnt) myidx = neighbor_idx[p0 + base + lane];

        for (int j = 0; j < cnt; j += 8) {
            const int m = min(8, cnt - j);   // uniform scalar

#define GLD(K, VK)                                                         \
            f32x4 VK = {0.f,0.f,0.f,0.f};                                  \
            if (K < m) {                                                   \
                const int nb = __shfl(myidx, j + K);                       \
                VK = *reinterpret_cast<const f32x4*>(                      \
                    ent + (size_t)nb * HH + lane * 4);                     \
            }
            GLD(0, v0) GLD(1, v1) GLD(2, v2) GLD(3, v3)
            GLD(4, v4) GLD(5, v5) GLD(6, v6) GLD(7, v7)
#undef GLD

#define ACC(K, VK)                                                         \
            if (K < m) {                                                   \
                const int p = base + j + K;                                \
                if      (p < r1) a0 += VK;                                 \
                else if (p < r2) a1 += VK;                                 \
                else if (p < r3) a2 += VK;                                 \
                else             a3 += VK;                                 \
            }
            ACC(0, v0) ACC(1, v1) ACC(2, v2) ACC(3, v3)
            ACC(4, v4) ACC(5, v5) ACC(6, v6) ACC(7, v7)
#undef ACC
        }
    }

    const float i0 = 1.0f / fmaxf((float)(p1 - p0), 1.0f);
    const float i1 = 1.0f / fmaxf((float)(p2 - p1), 1.0f);
    const float i2 = 1.0f / fmaxf((float)(p3 - p2), 1.0f);
    const float i3 = 1.0f / fmaxf((float)(p4 - p3), 1.0f);

    float* o = out + (size_t)seg0 * (3 * HH);
#define STROW(S, AV, INV)                                                  \
    {                                                                      \
        const f32x4 mm = AV * INV;                                         \
        float* os = o + (size_t)(S) * (3 * HH);                            \
        __builtin_nontemporal_store(mm, reinterpret_cast<f32x4*>(os) + lane); \
    }
    STROW(0, a0, i0) STROW(1, a1, i1) STROW(2, a2, i2) STROW(3, a3, i3)
#undef STROW
}

// ---------------------------------------------------------------------------
extern "C" void kernel_launch(void* const* d_in, const int* in_sizes, int n_in,
                              void* d_out, int out_size, void* d_ws, size_t ws_size,
                              hipStream_t stream) {
    const int*   neighbor_idx = (const int*)  d_in[0];
    const int*   segment_ids  = (const int*)  d_in[1];
    const int*   s_tem        = (const int*)  d_in[2];
    const int*   r_tem        = (const int*)  d_in[3];
    const float* s_hist_dt    = (const float*)d_in[4];
    const float* ent_embeds   = (const float*)d_in[5];
    const float* rel_embeds   = (const float*)d_in[6];
    float*       out          = (float*)d_out;

    int* start = (int*)d_ws;   // (NSEG+1) ints of scratch

    // Kernel 1: segment boundaries + dt tail copy
    {
        const int threads = 256;
        const int blocks  = (NSEGC + 1 + threads - 1) / threads;   // 257
        float* out_tail = out + (size_t)NSEGC * (3 * HH);
        seg_bounds_dt_kernel<<<blocks, threads, 0, stream>>>(
            segment_ids, start, s_hist_dt, out_tail);
    }

    // Kernel 2 FIRST: write-streaming broadcast of ent/rel rows.
    // Runs before the gather phase so its 134 MB stream cannot evict the
    // ent table from L3 while gathers are in flight.
    {
        broadcast_kernel<<<BB, 256, 0, stream>>>(
            s_tem, r_tem, ent_embeds, rel_embeds, out);
    }

    // Kernel 3 LAST: gather/mean phase with L3-resident table
    // (table 102 MB + mean writes 67 MB < 256 MB L3).
    {
        const int threads = 256;
        const int blocks  = NSEGC / SPW / 4;   // 4096 (divisible by 8)
        mean_kernel<<<blocks, threads, 0, stream>>>(
            neighbor_idx, ent_embeds, start, out);
    }
}

// Round 10
// 332.270 us; speedup vs baseline: 1.0349x; 1.0349x over previous
//
#include <hip/hip_runtime.h>
#include <hip/hip_bf16.h>

// Problem constants: B=2048, S=32, H=256, NSEG=65536, NNBR=524288, ENT=100000
#define BB    2048
#define SS    32
#define HH    256
#define NSEGC 65536
#define NNBRC 524288
#define NXCD  8
#define SEGW  8            // segments per wave
#define WPB   8            // waves per block (512 threads)
#define CHSH  11           // chunk = 2048 table rows = 2 MB
#define NCH   49           // ceil(100000 / 2048)
#define SENT  0x7FFFFFFF   // sentinel idx for inactive lanes (chunk never matches)

using f32x4 = __attribute__((ext_vector_type(4))) float;

// ---------------------------------------------------------------------------
// Kernel 1: per-segment lower_bound over sorted segment_ids -> start[NSEG+1]
//           + folded-in float4 copy of s_hist_dt into the output tail.
// ---------------------------------------------------------------------------
__global__ __launch_bounds__(256) void seg_bounds_dt_kernel(
    const int*   __restrict__ segment_ids,
    int*         __restrict__ start,
    const float* __restrict__ dt,
    float*       __restrict__ out_tail)
{
    const int i = blockIdx.x * blockDim.x + threadIdx.x;

    if (i < NSEGC / 4) {
        const f32x4 v = reinterpret_cast<const f32x4*>(dt)[i];
        __builtin_nontemporal_store(v, reinterpret_cast<f32x4*>(out_tail) + i);
    }

    if (i > NSEGC) return;
    int lo = 0, hi = NNBRC;
    while (lo < hi) {
        const int mid = (lo + hi) >> 1;
        if (segment_ids[mid] < i) lo = mid + 1;
        else hi = mid;
    }
    start[i] = lo;
}

// ---------------------------------------------------------------------------
// Kernel 2: table-sweep gather. One wave owns 8 consecutive segments
// (~64 pairs, held entirely in 3 idx registers). Each wave reorders its OWN
// gathers by table chunk (2 MB): outer loop over 49 chunks, ballot-extract
// the pairs whose idx falls in the chunk, gather, bucket-accumulate into 8
// named f32x4 accumulators via a scalar binary tree (p and boundaries are
// wave-uniform). All 8192 waves are co-resident (1024 blocks x 512 thr,
// 16 waves/CU at <=128 VGPR), so the whole device sweeps the table roughly
// front-to-back in ONE pass: compulsory table reads become near-sequential,
// re-references (5.2x/row) hit the L2/MALL-resident 2 MB window.
// ---------------------------------------------------------------------------
__global__ __launch_bounds__(512, 4) void sweep_kernel(
    const int*   __restrict__ neighbor_idx,
    const int*   __restrict__ s_tem,
    const int*   __restrict__ r_tem,
    const float* __restrict__ ent,
    const float* __restrict__ rel,
    const int*   __restrict__ start,
    float*       __restrict__ out)
{
    // chunked XCD swizzle (1024 % 8 == 0)
    const int chunkw = gridDim.x / NXCD;
    const int wg   = (blockIdx.x % NXCD) * chunkw + blockIdx.x / NXCD;
    const int wave = wg * WPB + (threadIdx.x >> 6);    // 0..8191
    const int lane = threadIdx.x & 63;
    const int seg0 = wave * SEGW;
    const int b    = seg0 >> 5;                        // batch (SEGW divides SS)

    // 9 boundaries start[seg0..seg0+8] -> scalar regs
    const int sv = start[seg0 + min(lane, SEGW)];
    const int p0 = __builtin_amdgcn_readfirstlane(__shfl(sv, 0));
    const int q1 = __builtin_amdgcn_readfirstlane(__shfl(sv, 1));
    const int q2 = __builtin_amdgcn_readfirstlane(__shfl(sv, 2));
    const int q3 = __builtin_amdgcn_readfirstlane(__shfl(sv, 3));
    const int q4 = __builtin_amdgcn_readfirstlane(__shfl(sv, 4));
    const int q5 = __builtin_amdgcn_readfirstlane(__shfl(sv, 5));
    const int q6 = __builtin_amdgcn_readfirstlane(__shfl(sv, 6));
    const int q7 = __builtin_amdgcn_readfirstlane(__shfl(sv, 7));
    const int q8 = __builtin_amdgcn_readfirstlane(__shfl(sv, 8));
    const int total = q8 - p0;
    const int r1 = q1-p0, r2 = q2-p0, r3 = q3-p0, r4 = q4-p0,
              r5 = q5-p0, r6 = q6-p0, r7 = q7-p0;

    f32x4 a0 = {0.f,0.f,0.f,0.f}, a1 = a0, a2 = a0, a3 = a0,
          a4 = a0, a5 = a0, a6 = a0, a7 = a0;

#define ACCUM(P, V)                                                        \
    {                                                                      \
        if ((P) < r4) {                                                    \
            if ((P) < r2) { if ((P) < r1) a0 += (V); else a1 += (V); }     \
            else          { if ((P) < r3) a2 += (V); else a3 += (V); }     \
        } else {                                                           \
            if ((P) < r6) { if ((P) < r5) a4 += (V); else a5 += (V); }     \
            else          { if ((P) < r7) a6 += (V); else a7 += (V); }     \
        }                                                                  \
    }

    // superblocks of 192 pairs (3 idx regs); normally a single iteration
    for (int sb = 0; sb < total; sb += 192) {
        const int scnt = min(192, total - sb);
        int idx0 = SENT, idx1 = SENT, idx2 = SENT;
        if (lane < scnt)       idx0 = neighbor_idx[p0 + sb + lane];
        if (64 + lane < scnt)  idx1 = neighbor_idx[p0 + sb + 64 + lane];
        if (128 + lane < scnt) idx2 = neighbor_idx[p0 + sb + 128 + lane];
        const int ch0 = idx0 >> CHSH;
        const int ch1 = idx1 >> CHSH;
        const int ch2 = idx2 >> CHSH;

        for (int c = 0; c < NCH; ++c) {
            unsigned long long m0 = __ballot(ch0 == c);
            unsigned long long m1 = __ballot(ch1 == c);
            unsigned long long m2 = __ballot(ch2 == c);

            while (m0) {
                const int l = __builtin_ctzll(m0); m0 &= m0 - 1;
                const int nb = __shfl(idx0, l);
                const f32x4 v = *reinterpret_cast<const f32x4*>(
                    ent + (size_t)nb * HH + lane * 4);
                ACCUM(sb + l, v);
            }
            while (m1) {
                const int l = __builtin_ctzll(m1); m1 &= m1 - 1;
                const int nb = __shfl(idx1, l);
                const f32x4 v = *reinterpret_cast<const f32x4*>(
                    ent + (size_t)nb * HH + lane * 4);
                ACCUM(sb + 64 + l, v);
            }
            while (m2) {
                const int l = __builtin_ctzll(m2); m2 &= m2 - 1;
                const int nb = __shfl(idx2, l);
                const f32x4 v = *reinterpret_cast<const f32x4*>(
                    ent + (size_t)nb * HH + lane * 4);
                ACCUM(sb + 128 + l, v);
            }
        }
    }
#undef ACCUM

    // epilogue: per-segment mean + broadcast ent/rel rows (NT stores)
    const int e = s_tem[b];
    const int r = r_tem[b];
    const f32x4 ev = *reinterpret_cast<const f32x4*>(ent + (size_t)e * HH + lane * 4);
    const f32x4 rv = *reinterpret_cast<const f32x4*>(rel + (size_t)r * HH + lane * 4);

    float* o = out + (size_t)seg0 * (3 * HH);
#define STROW(S, AV, CLO, CHI)                                             \
    {                                                                      \
        const float inv = 1.0f / fmaxf((float)((CHI) - (CLO)), 1.0f);      \
        const f32x4 mm = AV * inv;                                         \
        float* os = o + (size_t)(S) * (3 * HH);                            \
        __builtin_nontemporal_store(mm, reinterpret_cast<f32x4*>(os) + lane);          \
        __builtin_nontemporal_store(ev, reinterpret_cast<f32x4*>(os + HH) + lane);     \
        __builtin_nontemporal_store(rv, reinterpret_cast<f32x4*>(os + 2 * HH) + lane); \
    }
    STROW(0, a0, p0, q1) STROW(1, a1, q1, q2) STROW(2, a2, q2, q3)
    STROW(3, a3, q3, q4) STROW(4, a4, q4, q5) STROW(5, a5, q5, q6)
    STROW(6, a6, q6, q7) STROW(7, a7, q7, q8)
#undef STROW
}

// ---------------------------------------------------------------------------
extern "C" void kernel_launch(void* const* d_in, const int* in_sizes, int n_in,
                              void* d_out, int out_size, void* d_ws, size_t ws_size,
                              hipStream_t stream) {
    const int*   neighbor_idx = (const int*)  d_in[0];
    const int*   segment_ids  = (const int*)  d_in[1];
    const int*   s_tem        = (const int*)  d_in[2];
    const int*   r_tem        = (const int*)  d_in[3];
    const float* s_hist_dt    = (const float*)d_in[4];
    const float* ent_embeds   = (const float*)d_in[5];
    const float* rel_embeds   = (const float*)d_in[6];
    float*       out          = (float*)d_out;

    int* start = (int*)d_ws;   // (NSEG+1) ints of scratch

    // Kernel 1: segment boundaries + dt tail copy
    {
        const int threads = 256;
        const int blocks  = (NSEGC + 1 + threads - 1) / threads;   // 257
        float* out_tail = out + (size_t)NSEGC * (3 * HH);
        seg_bounds_dt_kernel<<<blocks, threads, 0, stream>>>(
            segment_ids, start, s_hist_dt, out_tail);
    }

    // Kernel 2: fully-resident table sweep.
    // 1024 blocks x 512 threads = 8192 waves = 16 waves/CU (all co-resident).
    {
        const int blocks = NSEGC / (SEGW * WPB);   // 1024 (divisible by 8)
        sweep_kernel<<<blocks, 512, 0, stream>>>(
            neighbor_idx, s_tem, r_tem, ent_embeds, rel_embeds, start, out);
    }
}